// Round 1
// baseline (259.305 us; speedup 1.0000x reference)
//
#include <hip/hip_runtime.h>
#include <math.h>

// Problem: B=8, C=64, T=16, H=64, W=64, text_dim=768
// out[b,c,:,h,w] = D^T diag(w[b,c,:]) D  @  r[b,c,:,h,w]
// w[b, c*16+k] = sigmoid(E_txt[b] . Wf[c*16+k] + bf[c*16+k])

#define HW 4096          // H*W
#define HW4 1024         // HW / 4
#define TDIM 16

// ---------------- Kernel 1: gate GEMM + sigmoid -> w[8][1024] ----------------
// grid = 32 blocks x 256 threads. thread = (ct_local = tid>>3, b = tid&7).
// E_txt (8x768 = 24 KB) staged in LDS with row stride 772 (768 % 32 == 0 would
// put all 8 b-rows in the same bank group).
__global__ __launch_bounds__(256) void gate_kernel(
    const float* __restrict__ E,    // (8, 768)
    const float* __restrict__ Wf,   // (1024, 768)
    const float* __restrict__ bf,   // (1024,)
    float* __restrict__ wout)       // (8, 1024)
{
    __shared__ float Es[8 * 772];
    const float4* E4 = (const float4*)E;
    for (int i = threadIdx.x; i < 1536; i += 256) {   // 8*192 float4
        int row = i / 192, col = i % 192;
        ((float4*)Es)[row * 193 + col] = E4[i];       // 193 f4 = 772 floats stride
    }
    __syncthreads();

    const int ct = blockIdx.x * 32 + (threadIdx.x >> 3);
    const int b  = threadIdx.x & 7;
    const float4* wrow = (const float4*)(Wf + ct * 768);
    const float4* erow = (const float4*)(Es + b * 772);

    float4 acc = make_float4(0.f, 0.f, 0.f, 0.f);
#pragma unroll 8
    for (int j = 0; j < 192; ++j) {
        float4 a = wrow[j];
        float4 e = erow[j];
        acc.x = fmaf(a.x, e.x, acc.x);
        acc.y = fmaf(a.y, e.y, acc.y);
        acc.z = fmaf(a.z, e.z, acc.z);
        acc.w = fmaf(a.w, e.w, acc.w);
    }
    float s = (acc.x + acc.y) + (acc.z + acc.w) + bf[ct];
    wout[b * 1024 + ct] = 1.0f / (1.0f + expf(-s));
}

// ---------------- Kernel 2: fused DCT -> gate -> IDCT ----------------
// grid = 2048 blocks (= 512 (b,c) pairs x 4 hw-chunks), 256 threads.
// Each thread handles one float4 of hw for all 16 t.
__global__ __launch_bounds__(256) void mod_kernel(
    const float* __restrict__ r,     // (B*C, 16, 4096)
    const float* __restrict__ wbuf,  // (8, 1024) == (B*C, 16)
    float* __restrict__ out)
{
    __shared__ float Dl[16][16];
    __shared__ float wv[16];
    __shared__ float Msh[16][17];

    const int tid   = threadIdx.x;
    const int bc    = blockIdx.x >> 2;   // 0..511
    const int chunk = blockIdx.x & 3;    // 0..3

    // D[k][n] = cos(pi*(n+0.5)*k/16) * sqrt(2/16); row 0 scaled by 1/sqrt(2) -> 0.25
    {
        int k = tid >> 4, n = tid & 15;
        float v = (k == 0) ? 0.25f
                           : cospif((n + 0.5f) * (float)k * (1.0f / 16.0f)) * 0.35355339059327373f;
        Dl[k][n] = v;
        if (tid < 16) wv[tid] = wbuf[bc * 16 + tid];
    }
    __syncthreads();

    // M[i][j] = sum_k D[k][i] * w[k] * D[k][j]
    {
        int i = tid >> 4, j = tid & 15;
        float s = 0.f;
#pragma unroll
        for (int k = 0; k < 16; ++k)
            s = fmaf(Dl[k][i] * wv[k], Dl[k][j], s);
        Msh[i][j] = s;
    }
    __syncthreads();

    const size_t base = (size_t)bc * (TDIM * HW);
    const float4* rp = (const float4*)(r + base);
    float4*       op = (float4*)(out + base);
    const int hw4 = chunk * 256 + tid;   // float4 index within 1024

    float4 x[16];
#pragma unroll
    for (int k = 0; k < 16; ++k)
        x[k] = rp[k * HW4 + hw4];

#pragma unroll
    for (int t = 0; t < 16; ++t) {
        float4 y = make_float4(0.f, 0.f, 0.f, 0.f);
#pragma unroll
        for (int k = 0; k < 16; ++k) {
            float m = Msh[t][k];
            y.x = fmaf(m, x[k].x, y.x);
            y.y = fmaf(m, x[k].y, y.y);
            y.z = fmaf(m, x[k].z, y.z);
            y.w = fmaf(m, x[k].w, y.w);
        }
        op[t * HW4 + hw4] = y;
    }
}

extern "C" void kernel_launch(void* const* d_in, const int* in_sizes, int n_in,
                              void* d_out, int out_size, void* d_ws, size_t ws_size,
                              hipStream_t stream) {
    const float* r    = (const float*)d_in[0];   // 33554432
    const float* E    = (const float*)d_in[1];   // 6144
    const float* Wf   = (const float*)d_in[2];   // 786432
    const float* bf   = (const float*)d_in[3];   // 1024
    float* out = (float*)d_out;
    float* w   = (float*)d_ws;                   // 8192 floats = 32 KB scratch

    gate_kernel<<<32, 256, 0, stream>>>(E, Wf, bf, w);
    mod_kernel<<<2048, 256, 0, stream>>>(r, w, out);
}

// Round 2
// 243.966 us; speedup vs baseline: 1.0629x; 1.0629x over previous
//
#include <hip/hip_runtime.h>
#include <math.h>

// Problem: B=8, C=64, T=16, H=64, W=64, text_dim=768
// out[b,c,:,h,w] = D^T diag(w[b,c,:]) D @ r[b,c,:,h,w]
// w[b, c*16+k] = sigmoid(E_txt[b] . Wf[c*16+k] + bf[c*16+k])
// Note w[b*1024 + c*16 + k] == w[bc*16 + k] with bc = b*64+c.

#define HW4 1024         // H*W/4 (float4 units)

// ---------------- Kernel A: gate GEMM + sigmoid -> w[8192] ----------------
// 256 blocks x 256 threads; one WAVE per ct row (1024 ct total).
// Lane j of the wave handles f4 positions {0,64,128}+lane of the 192-f4 row
// (fully coalesced), accumulates 8 per-b dots, butterfly-reduces over 64 lanes.
__global__ __launch_bounds__(256) void gate_kernel(
    const float* __restrict__ E,    // (8, 768)
    const float* __restrict__ Wf,   // (1024, 768)
    const float* __restrict__ bf,   // (1024,)
    float* __restrict__ wout)       // (8192,) indexed [bc*16+k]
{
    const int wave = threadIdx.x >> 6;
    const int lane = threadIdx.x & 63;
    const int ct   = blockIdx.x * 4 + wave;

    const float4* W4 = (const float4*)(Wf) + ct * 192;
    const float4* E4 = (const float4*)E;

    float acc[8];
#pragma unroll
    for (int b = 0; b < 8; ++b) acc[b] = 0.f;

#pragma unroll
    for (int j = 0; j < 3; ++j) {
        float4 a = W4[j * 64 + lane];
#pragma unroll
        for (int b = 0; b < 8; ++b) {
            float4 e = E4[b * 192 + j * 64 + lane];
            acc[b] = fmaf(a.x, e.x, acc[b]);
            acc[b] = fmaf(a.y, e.y, acc[b]);
            acc[b] = fmaf(a.z, e.z, acc[b]);
            acc[b] = fmaf(a.w, e.w, acc[b]);
        }
    }
    // 64-lane butterfly reduction for all 8 accumulators
#pragma unroll
    for (int off = 32; off >= 1; off >>= 1) {
#pragma unroll
        for (int b = 0; b < 8; ++b)
            acc[b] += __shfl_xor(acc[b], off, 64);
    }
    const float bias = bf[ct];
#pragma unroll
    for (int b = 0; b < 8; ++b) {
        if (lane == b) {
            float s = acc[b] + bias;
            // wout index: b*1024 + ct  ==  bc*16 + k  layout
            wout[b * 1024 + ct] = 1.0f / (1.0f + expf(-s));
        }
    }
}

// ---------------- Kernel B: build M[bc][16][16] = D^T diag(w) D ----------------
// 512 blocks x 256 threads; thread (i = tid>>4, j = tid&15) computes one entry.
__global__ __launch_bounds__(256) void buildM_kernel(
    const float* __restrict__ wbuf,  // (8192,) [bc*16+k]
    float* __restrict__ Mout)        // (512, 256)
{
    __shared__ float Dl[16][16];
    __shared__ float wv[16];
    const int tid = threadIdx.x;
    const int bc  = blockIdx.x;
    {
        int k = tid >> 4, n = tid & 15;
        float v = (k == 0) ? 0.25f
                           : cospif((n + 0.5f) * (float)k * (1.0f / 16.0f)) * 0.35355339059327373f;
        Dl[k][n] = v;
        if (tid < 16) wv[tid] = wbuf[bc * 16 + tid];
    }
    __syncthreads();
    int i = tid >> 4, j = tid & 15;
    float s = 0.f;
#pragma unroll
    for (int k = 0; k < 16; ++k)
        s = fmaf(Dl[k][i] * wv[k], Dl[k][j], s);
    Mout[bc * 256 + tid] = s;   // tid == i*16+j, coalesced
}

// ---------------- Kernel C: y = M @ x streaming transform ----------------
// 8192 blocks x 64 threads (1 wave). bc = blk>>4, chunk = blk&15 (64 f4 of hw).
// k-major accumulation: compute starts as soon as x[0] lands (vmcnt(15)),
// smearing memory demand across the whole wave lifetime (anti-convoy).
__global__ __launch_bounds__(64) void mod_kernel(
    const float* __restrict__ r,     // (512, 16, 4096)
    const float* __restrict__ M,     // (512, 256)
    float* __restrict__ out)
{
    __shared__ float4 Ms4[64];
    const int lane  = threadIdx.x;
    const int bc    = blockIdx.x >> 4;
    const int chunk = blockIdx.x & 15;

    Ms4[lane] = ((const float4*)(M + bc * 256))[lane];   // 256 floats, 1 coalesced load
    __syncthreads();
    const float* Ms = (const float*)Ms4;   // Ms[t*16+k]

    const size_t base = (size_t)bc * (16 * 4096);
    const float4* rp = (const float4*)(r + base);
    float4*       op = (float4*)(out + base);
    const int col = chunk * 64 + lane;

    float4 x[16];
#pragma unroll
    for (int k = 0; k < 16; ++k)
        x[k] = rp[k * HW4 + col];

    float4 y[16];
#pragma unroll
    for (int t = 0; t < 16; ++t)
        y[t] = make_float4(0.f, 0.f, 0.f, 0.f);

#pragma unroll
    for (int k = 0; k < 16; ++k) {
        float4 xk = x[k];
#pragma unroll
        for (int t = 0; t < 16; ++t) {
            float m = Ms[t * 16 + k];
            y[t].x = fmaf(m, xk.x, y[t].x);
            y[t].y = fmaf(m, xk.y, y[t].y);
            y[t].z = fmaf(m, xk.z, y[t].z);
            y[t].w = fmaf(m, xk.w, y[t].w);
        }
    }

#pragma unroll
    for (int t = 0; t < 16; ++t)
        op[t * HW4 + col] = y[t];
}

extern "C" void kernel_launch(void* const* d_in, const int* in_sizes, int n_in,
                              void* d_out, int out_size, void* d_ws, size_t ws_size,
                              hipStream_t stream) {
    const float* r  = (const float*)d_in[0];   // 33554432
    const float* E  = (const float*)d_in[1];   // 6144
    const float* Wf = (const float*)d_in[2];   // 786432
    const float* bf = (const float*)d_in[3];   // 1024
    float* out = (float*)d_out;
    float* w   = (float*)d_ws;                  // 8192 floats
    float* M   = (float*)d_ws + 8192;           // 512*256 floats

    gate_kernel  <<<256, 256, 0, stream>>>(E, Wf, bf, w);
    buildM_kernel<<<512, 256, 0, stream>>>(w, M);
    mod_kernel   <<<8192, 64, 0, stream>>>(r, M, out);
}